// Round 10
// baseline (24.272 us; speedup 1.0000x reference)
//
#include <hip/hip_runtime.h>

#define NQ 11
#define NC 3
#define NANG (NC * 66)
#define BLOCK 1024

typedef float f2 __attribute__((ext_vector_type(2)));

__device__ __forceinline__ f2 swp(f2 v) { return __builtin_shufflevector(v, v, 1, 0); }

// DPP quad_perm: 0xB1 = xor1, 0x4E = xor2
template<int CTRL>
__device__ __forceinline__ float dppx(float v) {
  return __int_as_float(__builtin_amdgcn_update_dpp(
      0, __float_as_int(v), CTRL, 0xF, 0xF, false));
}
template<int CTRL>
__device__ __forceinline__ f2 dpp2(f2 v) {
  f2 r; r.x = dppx<CTRL>(v.x); r.y = dppx<CTRL>(v.y); return r;
}
// ds_swizzle BitMode xor patterns: xor4 = 0x101F, xor8 = 0x201F
template<int OFF>
__device__ __forceinline__ float swz1(float v) {
  return __int_as_float(__builtin_amdgcn_ds_swizzle(__float_as_int(v), OFF));
}
template<int OFF>
__device__ __forceinline__ f2 swz2(f2 v) {
  f2 r; r.x = swz1<OFF>(v.x); r.y = swz1<OFF>(v.y); return r;
}
// gfx950 permlane swaps (VALU pipe)
__device__ __forceinline__ float plp16(float v, int lane) {
  auto r = __builtin_amdgcn_permlane16_swap(__float_as_int(v), __float_as_int(v), false, false);
  return __int_as_float((lane & 16) ? r[0] : r[1]);
}
__device__ __forceinline__ float plp32(float v, int lane) {
  auto r = __builtin_amdgcn_permlane32_swap(__float_as_int(v), __float_as_int(v), false, false);
  return __int_as_float((lane & 32) ? r[0] : r[1]);
}
__device__ __forceinline__ f2 plp16_2(f2 v, int lane) {
  f2 r; r.x = plp16(v.x, lane); r.y = plp16(v.y, lane); return r;
}
__device__ __forceinline__ f2 plp32_2(f2 v, int lane) {
  f2 r; r.x = plp32(v.x, lane); r.y = plp32(v.y, lane); return r;
}
__device__ __forceinline__ float plsum16(float v) {
  auto r = __builtin_amdgcn_permlane16_swap(__float_as_int(v), __float_as_int(v), false, false);
  return __int_as_float(r[0]) + __int_as_float(r[1]);
}
__device__ __forceinline__ float plsum32(float v) {
  auto r = __builtin_amdgcn_permlane32_swap(__float_as_int(v), __float_as_int(v), false, false);
  return __int_as_float(r[0]) + __int_as_float(r[1]);
}

// SU(2) U = [[a,b],[-conj(b),conj(a)]] as float4 (ar,ai,br,bi).
// In-thread pair apply: (v0,v1) <- U (v0,v1)
__device__ __forceinline__ void apply2p(f2& v0, f2& v1, float4 U) {
  const f2 ai2 = {-U.y, U.y};
  const f2 bi2 = {-U.w, U.w};
  const f2 w0 = swp(v0), w1 = swp(v1);
  const f2 n0 =  U.x * v0 + ai2 * w0 + U.z * v1 + bi2 * w1;
  const f2 n1 = -U.z * v0 + bi2 * w0 + U.x * v1 - ai2 * w1;
  v0 = n0; v1 = n1;
}
// own/partner row apply: v <- row(hi) of U applied to (own=v, partner=p)
__device__ __forceinline__ void gpartp(f2& v, f2 p, float4 U, bool hi) {
  const f2 ai2 = hi ? f2{U.y, -U.y} : f2{-U.y, U.y};
  const float br = hi ? -U.z : U.z;
  const f2 bi2 = {-U.w, U.w};
  v = U.x * v + ai2 * swp(v) + br * p + bi2 * swp(p);
}

// wave-bit gate via LDS exchange (2 f2 per thread)
template<int WVX>
__device__ __forceinline__ void g_wave(f2& s0, f2& s1, float4 U,
                                       f2* __restrict__ buf, int wave, int lane) {
  const int idx = (wave << 6) | lane;
  buf[idx] = s0; buf[1024 + idx] = s1;
  __syncthreads();
  const int p = ((wave ^ WVX) << 6) | lane;
  const bool hi = (wave & WVX) != 0;
  gpartp(s0, buf[p], U, hi);
  gpartp(s1, buf[1024 + p], U, hi);
}

__global__ __launch_bounds__(BLOCK, 8) void qsim_kernel(
    const float* __restrict__ x, const float* __restrict__ W,
    const float* __restrict__ bias, float* __restrict__ out) {
  const int bidx = blockIdx.x;
  const int tid = threadIdx.x;
  const int lane = tid & 63, wave = tid >> 6;   // wave 0..15

  __shared__ float xs[NQ];
  __shared__ float ang[NANG];
  __shared__ float4 m1s[NC * NQ];   // fused 1q matrices (SU2)
  __shared__ float4 m2s[NC * NQ];   // fused controlled matrices (SU2)
  __shared__ float4 v1s[NC * 10];   // V[t] = m2[t-1] * m1[t], t=1..10
  __shared__ f2 ex0[2048];
  __shared__ f2 ex1[2048];
  __shared__ float red[16][24];

  if (tid < NQ) xs[tid] = x[bidx * NQ + tid];
  __syncthreads();

  if (tid < NANG) {
    const int c = tid / 66, o = tid - c * 66;
    const float* wr = W + (c * 66 + o) * NQ;
    float s = bias[c * 66 + o];
#pragma unroll
    for (int i = 0; i < NQ; ++i) s += wr[i] * xs[i];
    ang[tid] = s;
  }
  __syncthreads();

  if (tid < 2 * NC * NQ) {
    const int kind = tid / (NC * NQ);
    const int id = tid - kind * (NC * NQ);
    const int c = id / NQ, q = id - c * NQ;
    const float* a = ang + c * 66;
    if (kind == 0) {
      // U = RZ(a3) RY(a2) RZ(a1) RY(a0), SU2 form (a,b)
      float s0,c0,s1,c1,s2,c2,s3,c3;
      sincosf(0.5f*a[q],      &s0,&c0);
      sincosf(0.5f*a[11+q],   &s1,&c1);
      sincosf(0.5f*a[22+q],   &s2,&c2);
      sincosf(0.5f*a[33+q],   &s3,&c3);
      const float mar = c1*c0, mai = -s1*c0;
      const float mbr = -c1*s0, mbi = s1*s0;
      const float nar = c2*mar + s2*mbr, nai = c2*mai - s2*mbi;
      const float nbr = c2*mbr - s2*mar, nbi = c2*mbi + s2*mai;
      m1s[id] = make_float4(c3*nar + s3*nai, c3*nai - s3*nar,
                            c3*nbr + s3*nbi, c3*nbi - s3*nbr);
    } else {
      // U = RZ(a5) RY(a4)
      float s4,c4,s5,c5;
      sincosf(0.5f*a[44+q], &s4,&c4);
      sincosf(0.5f*a[55+q], &s5,&c5);
      m2s[id] = make_float4(c5*c4, -s5*c4, -c5*s4, s5*s4);
    }
  }
  __syncthreads();

  // V[c][t] = m2[c][t-1] * m1[c][t]  (SU2 product)
  if (tid < NC * 10) {
    const int c = tid / 10, tt = tid - c * 10, t = tt + 1;
    const float4 A = m2s[c*NQ + t - 1];
    const float4 B = m1s[c*NQ + t];
    const float pr_=A.x, pi_=A.y, qr_=A.z, qi_=A.w;
    const float ar_=B.x, ai_=B.y, br_=B.z, bi_=B.w;
    v1s[c*10 + tt] = make_float4(
      (pr_*ar_ - pi_*ai_) - (qr_*br_ + qi_*bi_),
      (pr_*ai_ + pi_*ar_) - (qi_*br_ - qr_*bi_),
      (pr_*br_ - pi_*bi_) + (qr_*ar_ + qi_*ai_),
      (pr_*bi_ + pi_*br_) + (qi_*ar_ - qr_*ai_));
  }
  __syncthreads();

  // amp bits: [0]=reg <-> q0 ; [6:1]=lane bits L0..L5 <-> q10,q9,q8,q3,q2,q1 ;
  // [10:7]=wave bits W0..W3 <-> q7,q6,q5,q4
  f2 s0 = {0.f, 0.f}, s1 = {0.f, 0.f};
  if (tid == 0) s0.x = 1.f;

  for (int c = 0; c < NC; ++c) {
    const float4* M1 = &m1s[c * NQ];
    const float4* VF = &v1s[c * 10];
    // e0: 1q(q0), reg bit
    apply2p(s0, s1, M1[0]);
    { // e1: F(1|0): target q1 (lane b5), ctrl q0 = reg -> per-amp U
      const bool hi = (lane & 32) != 0;
      gpartp(s0, plp32_2(s0, lane), M1[1], hi);
      gpartp(s1, plp32_2(s1, lane), VF[0], hi);
    }
    { // e2: F(2|1): target q2 (lane b4), ctrl q1 (lane b5)
      const float4 U = *((lane & 32) ? &VF[1] : &M1[2]);
      const bool hi = (lane & 16) != 0;
      gpartp(s0, plp16_2(s0, lane), U, hi);
      gpartp(s1, plp16_2(s1, lane), U, hi);
    }
    { // e3: F(3|2): target q3 (lane b3), ctrl q2 (lane b4)
      const float4 U = *((lane & 16) ? &VF[2] : &M1[3]);
      const bool hi = (lane & 8) != 0;
      gpartp(s0, swz2<0x201F>(s0), U, hi);
      gpartp(s1, swz2<0x201F>(s1), U, hi);
    }
    // e4: F(4|3): target q4 (wave b3), ctrl q3 (lane b3)
    g_wave<8>(s0, s1, *((lane & 8) ? &VF[3] : &M1[4]), ex0, wave, lane);
    // e5: F(5|4): target q5 (wave b2), ctrl q4 (wave b3)
    g_wave<4>(s0, s1, *((wave & 8) ? &VF[4] : &M1[5]), ex1, wave, lane);
    // e6: F(6|5): target q6 (wave b1), ctrl q5 (wave b2)
    g_wave<2>(s0, s1, *((wave & 4) ? &VF[5] : &M1[6]), ex0, wave, lane);
    // e7: F(7|6): target q7 (wave b0), ctrl q6 (wave b1)
    g_wave<1>(s0, s1, *((wave & 2) ? &VF[6] : &M1[7]), ex1, wave, lane);
    { // e8: F(8|7): target q8 (lane b2), ctrl q7 (wave b0)
      const float4 U = *((wave & 1) ? &VF[7] : &M1[8]);
      const bool hi = (lane & 4) != 0;
      gpartp(s0, swz2<0x101F>(s0), U, hi);
      gpartp(s1, swz2<0x101F>(s1), U, hi);
    }
    { // e9: F(9|8): target q9 (lane b1), ctrl q8 (lane b2)
      const float4 U = *((lane & 4) ? &VF[8] : &M1[9]);
      const bool hi = (lane & 2) != 0;
      gpartp(s0, dpp2<0x4E>(s0), U, hi);
      gpartp(s1, dpp2<0x4E>(s1), U, hi);
    }
    { // e10: F(10|9): target q10 (lane b0), ctrl q9 (lane b1)
      const float4 U = *((lane & 2) ? &VF[9] : &M1[10]);
      const bool hi = (lane & 1) != 0;
      gpartp(s0, dpp2<0xB1>(s0), U, hi);
      gpartp(s1, dpp2<0xB1>(s1), U, hi);
    }
    { // e11: C(10->0): ctrl q10 (lane b0), target q0 (reg) — per-lane masked pair apply
      const float4 Uc = m2s[c * NQ + 10];
      const float4 U = (lane & 1) ? Uc : make_float4(1.f, 0.f, 0.f, 0.f);
      apply2p(s0, s1, U);
    }
  }

  // ---- expectations ----
  const int idx = (wave << 6) | lane;
  ex0[idx] = s0; ex0[1024 + idx] = s1;
  __syncthreads();
  const int p8 = ((wave ^ 8) << 6) | lane;
  const int p4 = ((wave ^ 4) << 6) | lane;
  const int p2 = ((wave ^ 2) << 6) | lane;
  const int p1 = ((wave ^ 1) << 6) | lane;
  f2 t;
  t = s0*ex0[p8] + s1*ex0[1024+p8]; const float xq4 = t.x + t.y;
  t = s0*ex0[p4] + s1*ex0[1024+p4]; const float xq5 = t.x + t.y;
  t = s0*ex0[p2] + s1*ex0[1024+p2]; const float xq6 = t.x + t.y;
  t = s0*ex0[p1] + s1*ex0[1024+p1]; const float xq7 = t.x + t.y;

  const f2 mg0 = s0 * s0, mg1 = s1 * s1;
  const float m0 = mg0.x + mg0.y, m1 = mg1.x + mg1.y;
  const float ztot = m0 + m1;
  const float zq0 = m0 - m1;
  t = s0 * s1; const float xq0 = 2.f * (t.x + t.y);
  t = s0*plp32_2(s0,lane) + s1*plp32_2(s1,lane); const float xq1 = t.x + t.y;
  t = s0*plp16_2(s0,lane) + s1*plp16_2(s1,lane); const float xq2 = t.x + t.y;
  t = s0*swz2<0x201F>(s0) + s1*swz2<0x201F>(s1); const float xq3 = t.x + t.y;
  t = s0*swz2<0x101F>(s0) + s1*swz2<0x101F>(s1); const float xq8 = t.x + t.y;
  t = s0*dpp2<0x4E>(s0)  + s1*dpp2<0x4E>(s1);  const float xq9 = t.x + t.y;
  t = s0*dpp2<0xB1>(s0)  + s1*dpp2<0xB1>(s1);  const float xq10 = t.x + t.y;

  float v[22];
  v[0]=xq0; v[1]=xq1; v[2]=xq2; v[3]=xq3; v[4]=xq4; v[5]=xq5; v[6]=xq6;
  v[7]=xq7; v[8]=xq8; v[9]=xq9; v[10]=xq10;
  v[11] = zq0;
  v[12] = (lane & 32) ? -ztot : ztot;   // Z q1
  v[13] = (lane & 16) ? -ztot : ztot;   // Z q2
  v[14] = (lane & 8)  ? -ztot : ztot;   // Z q3
  v[15] = (wave & 8)  ? -ztot : ztot;   // Z q4
  v[16] = (wave & 4)  ? -ztot : ztot;   // Z q5
  v[17] = (wave & 2)  ? -ztot : ztot;   // Z q6
  v[18] = (wave & 1)  ? -ztot : ztot;   // Z q7
  v[19] = (lane & 4)  ? -ztot : ztot;   // Z q8
  v[20] = (lane & 2)  ? -ztot : ztot;   // Z q9
  v[21] = (lane & 1)  ? -ztot : ztot;   // Z q10

  // reduction: DPP quad levels, pack 4/reg, ds_swizzle xor4/8, permlane 16/32
#pragma unroll
  for (int k = 0; k < 22; ++k) {
    v[k] += dppx<0xB1>(v[k]);
    v[k] += dppx<0x4E>(v[k]);
  }
  const int q4l = lane & 3;
  float wv[6];
#pragma unroll
  for (int p = 0; p < 5; ++p)
    wv[p] = q4l == 0 ? v[4*p] : (q4l == 1 ? v[4*p+1] : (q4l == 2 ? v[4*p+2] : v[4*p+3]));
  wv[5] = q4l == 0 ? v[20] : (q4l == 1 ? v[21] : 0.f);
#pragma unroll
  for (int p = 0; p < 6; ++p) {
    wv[p] += swz1<0x101F>(wv[p]);
    wv[p] += swz1<0x201F>(wv[p]);
    wv[p] = plsum16(wv[p]);
    wv[p] = plsum32(wv[p]);
  }
  if (lane < 4) {
#pragma unroll
    for (int p = 0; p < 6; ++p) red[wave][4*p + lane] = wv[p];
  }
  __syncthreads();
  if (tid < 22) {
    float sacc = 0.f;
#pragma unroll
    for (int w16 = 0; w16 < 16; ++w16) sacc += red[w16][tid];
    out[bidx * 22 + tid] = sacc;
  }
}

extern "C" void kernel_launch(void* const* d_in, const int* in_sizes, int n_in,
                              void* d_out, int out_size, void* d_ws, size_t ws_size,
                              hipStream_t stream) {
  (void)n_in; (void)d_ws; (void)ws_size; (void)out_size;
  const float* x = (const float*)d_in[0];
  const float* W = (const float*)d_in[1];
  const float* b = (const float*)d_in[2];
  float* out = (float*)d_out;
  const int batch = in_sizes[0] / NQ;
  qsim_kernel<<<batch, BLOCK, 0, stream>>>(x, W, b, out);
}